// Round 10
// baseline (99.968 us; speedup 1.0000x reference)
//
#include <hip/hip_runtime.h>
#include <hip/hip_bf16.h>

// Problem constants: M=100000 points, K=27 offsets, Cin=Cout=64.
// R10: fp8 + issue-order-correct register pipeline (A distance-4, B distance-2,
// loads reloaded AFTER consumption so every MFMA's needed loads are the oldest
// outstanding -> counted vmcnt leaves younger prefetches in flight), plus
// non-temporal hints on all streaming traffic to protect L2/L3 residency of
// the 6.4MB gather table.
#define NPTS 100000
#define KOFF 27
#define KPAD 28          // padded K: tile 27 = zero weights + zero-row gathers
#define NCH  64

typedef __attribute__((ext_vector_type(4))) float f32x4;
typedef __attribute__((ext_vector_type(4))) unsigned int u32x4;

// feats fp32 (M x 64) -> fp8 e4m3 (M+1 x 64); row NPTS all-zero.
__global__ void convert_feats_kernel(const float* __restrict__ feats,
                                     unsigned char* __restrict__ f8) {
  size_t tid  = (size_t)blockIdx.x * blockDim.x + threadIdx.x;
  size_t base = tid * 16;
  const size_t valid = (size_t)NPTS * NCH;      // 6,400,000 (divisible by 16)
  const size_t total = valid + NCH;             // + zero row
  if (base >= total) return;
  unsigned int w0 = 0, w1 = 0, w2 = 0, w3 = 0;
  if (base < valid) {
    const float4 a = *reinterpret_cast<const float4*>(feats + base);
    const float4 b = *reinterpret_cast<const float4*>(feats + base + 4);
    const float4 c = *reinterpret_cast<const float4*>(feats + base + 8);
    const float4 d = *reinterpret_cast<const float4*>(feats + base + 12);
    int p;
    p = __builtin_amdgcn_cvt_pk_fp8_f32(a.x, a.y, 0, false);
    p = __builtin_amdgcn_cvt_pk_fp8_f32(a.z, a.w, p, true);  w0 = (unsigned)p;
    p = __builtin_amdgcn_cvt_pk_fp8_f32(b.x, b.y, 0, false);
    p = __builtin_amdgcn_cvt_pk_fp8_f32(b.z, b.w, p, true);  w1 = (unsigned)p;
    p = __builtin_amdgcn_cvt_pk_fp8_f32(c.x, c.y, 0, false);
    p = __builtin_amdgcn_cvt_pk_fp8_f32(c.z, c.w, p, true);  w2 = (unsigned)p;
    p = __builtin_amdgcn_cvt_pk_fp8_f32(d.x, d.y, 0, false);
    p = __builtin_amdgcn_cvt_pk_fp8_f32(d.z, d.w, p, true);  w3 = (unsigned)p;
  }
  *reinterpret_cast<u32x4*>(f8 + base) = u32x4{w0, w1, w2, w3};
}

// weight fp32 [k][cin][cout] -> fp8 e4m3 lane-major fragment layout:
// fragment (ko, nt=o>>4, chunk=c>>5) contiguous 512B; lane L's 8B at L*8;
// byte j = c&7; lane = ((c>>3)&3)*16 + (o&15). Pad tile 27 zeros.
__global__ void convert_weight_kernel(const float* __restrict__ w,
                                      unsigned char* __restrict__ wt) {
  int tid = blockIdx.x * 256 + threadIdx.x;
  if (tid >= KPAD * NCH * NCH) return;
  int ko  = tid >> 12;
  int rem = tid & 4095;
  int c   = rem >> 6;
  int o   = rem & 63;
  float val = (ko < KOFF) ? w[(size_t)ko * 4096 + c * 64 + o] : 0.0f;
  int p = __builtin_amdgcn_cvt_pk_fp8_f32(val, 0.0f, 0, false);
  int dst = (ko * 8 + (o >> 4) * 2 + (c >> 5)) * 512
          + (((c >> 3) & 3) * 16 + (o & 15)) * 8 + (c & 7);
  wt[dst] = (unsigned char)(p & 0xff);
}

// Main kernel: block = 128 rows, 4 waves; wave owns 32 rows (2 row-tiles of
// 16) x 64 cout x all 28 kos.
__global__ __launch_bounds__(256, 4)
void spconv_kernel(const unsigned char* __restrict__ f8,       // (NPTS+1) x 64 fp8
                   const int* __restrict__ rulebook,           // NPTS x 27 int32
                   const unsigned char* __restrict__ wl,       // lane-major fp8 weights
                   const float* __restrict__ feats,            // NPTS x 64 fp32 (residual)
                   const float* __restrict__ bias,             // 64 fp32
                   float* __restrict__ out) {                  // NPTS x 64 fp32
  __shared__ int s_off[128][KPAD];   // BYTE offsets into f8 (idx*64)
  __shared__ int s_cnt[128];

  const int tid = threadIdx.x;
  const int m0  = blockIdx.x * 128;

  if (tid < 128) s_cnt[tid] = 0;
  __syncthreads();

  for (int f = tid; f < 128 * KPAD; f += 256) {
    int r = f / KPAD, k = f - r * KPAD;
    int m = m0 + r;
    int off = NPTS * 64;
    if (m < NPTS && k < KOFF) {
      int v = __builtin_nontemporal_load(&rulebook[(size_t)m * KOFF + k]);
      if (v >= 0) { off = v * 64; atomicAdd(&s_cnt[r], 1); }
    }
    s_off[r][k] = off;
  }
  __syncthreads();

  const int wave = tid >> 6;
  const int lane = tid & 63;
  const int lr   = lane & 15;
  const int lk   = lane >> 4;
  const int lk8  = lk * 8;             // byte offset within a 32B cin-chunk
  const int row0 = wave * 32 + lr;
  const int row1 = wave * 32 + 16 + lr;

  const char* fbase = (const char*)f8;
  const char* wlane = (const char*)wl + lane * 8;

  f32x4 acc0[4] = {f32x4{0,0,0,0}, f32x4{0,0,0,0}, f32x4{0,0,0,0}, f32x4{0,0,0,0}};
  f32x4 acc1[4] = {f32x4{0,0,0,0}, f32x4{0,0,0,0}, f32x4{0,0,0,0}, f32x4{0,0,0,0}};

  // A: 4 sets (distance 4). Per set: t0c0,t0c1,t1c0,t1c1 (row-tile, cin-chunk).
  long A0_0, A0_1, A0_2, A0_3;
  long A1_0, A1_1, A1_2, A1_3;
  long A2_0, A2_1, A2_2, A2_3;
  long A3_0, A3_1, A3_2, A3_3;
  // B: 2 sets (distance 2), 8 longs each.
  long Bx0, Bx1, Bx2, Bx3, Bx4, Bx5, Bx6, Bx7;
  long By0, By1, By2, By3, By4, By5, By6, By7;

#define LOADA(S0, S1, S2, S3, KO) {                                           \
    const int o0_ = s_off[row0][(KO)];                                        \
    const int o1_ = s_off[row1][(KO)];                                        \
    const char* p0_ = fbase + (size_t)(unsigned)o0_;                          \
    const char* p1_ = fbase + (size_t)(unsigned)o1_;                          \
    S0 = *reinterpret_cast<const long*>(p0_ + lk8);                           \
    S1 = *reinterpret_cast<const long*>(p0_ + 32 + lk8);                      \
    S2 = *reinterpret_cast<const long*>(p1_ + lk8);                           \
    S3 = *reinterpret_cast<const long*>(p1_ + 32 + lk8);                      \
  }

#define LOADB(B0, B1, B2, B3, B4, B5, B6, B7, KO) {                           \
    const char* wb_ = wlane + (size_t)(KO) * 4096;                            \
    B0 = *reinterpret_cast<const long*>(wb_ + 0 * 512);                       \
    B1 = *reinterpret_cast<const long*>(wb_ + 1 * 512);                       \
    B2 = *reinterpret_cast<const long*>(wb_ + 2 * 512);                       \
    B3 = *reinterpret_cast<const long*>(wb_ + 3 * 512);                       \
    B4 = *reinterpret_cast<const long*>(wb_ + 4 * 512);                       \
    B5 = *reinterpret_cast<const long*>(wb_ + 5 * 512);                       \
    B6 = *reinterpret_cast<const long*>(wb_ + 6 * 512);                       \
    B7 = *reinterpret_cast<const long*>(wb_ + 7 * 512);                       \
  }

#define MFMA_STEP(S0, S1, S2, S3, B0, B1, B2, B3, B4, B5, B6, B7) {           \
    acc0[0] = __builtin_amdgcn_mfma_f32_16x16x32_fp8_fp8(S0, B0, acc0[0],0,0,0);\
    acc0[0] = __builtin_amdgcn_mfma_f32_16x16x32_fp8_fp8(S1, B1, acc0[0],0,0,0);\
    acc1[0] = __builtin_amdgcn_mfma_f32_16x16x32_fp8_fp8(S2, B0, acc1[0],0,0,0);\
    acc1[0] = __builtin_amdgcn_mfma_f32_16x16x32_fp8_fp8(S3, B1, acc1[0],0,0,0);\
    acc0[1] = __builtin_amdgcn_mfma_f32_16x16x32_fp8_fp8(S0, B2, acc0[1],0,0,0);\
    acc0[1] = __builtin_amdgcn_mfma_f32_16x16x32_fp8_fp8(S1, B3, acc0[1],0,0,0);\
    acc1[1] = __builtin_amdgcn_mfma_f32_16x16x32_fp8_fp8(S2, B2, acc1[1],0,0,0);\
    acc1[1] = __builtin_amdgcn_mfma_f32_16x16x32_fp8_fp8(S3, B3, acc1[1],0,0,0);\
    acc0[2] = __builtin_amdgcn_mfma_f32_16x16x32_fp8_fp8(S0, B4, acc0[2],0,0,0);\
    acc0[2] = __builtin_amdgcn_mfma_f32_16x16x32_fp8_fp8(S1, B5, acc0[2],0,0,0);\
    acc1[2] = __builtin_amdgcn_mfma_f32_16x16x32_fp8_fp8(S2, B4, acc1[2],0,0,0);\
    acc1[2] = __builtin_amdgcn_mfma_f32_16x16x32_fp8_fp8(S3, B5, acc1[2],0,0,0);\
    acc0[3] = __builtin_amdgcn_mfma_f32_16x16x32_fp8_fp8(S0, B6, acc0[3],0,0,0);\
    acc0[3] = __builtin_amdgcn_mfma_f32_16x16x32_fp8_fp8(S1, B7, acc0[3],0,0,0);\
    acc1[3] = __builtin_amdgcn_mfma_f32_16x16x32_fp8_fp8(S2, B6, acc1[3],0,0,0);\
    acc1[3] = __builtin_amdgcn_mfma_f32_16x16x32_fp8_fp8(S3, B7, acc1[3],0,0,0);\
  }

  // Prologue: B(0),B(1) first (so the first MFMA's drain-to-A(0) covers them),
  // then A(0..3). One-time pipeline fill.
  LOADB(Bx0,Bx1,Bx2,Bx3,Bx4,Bx5,Bx6,Bx7, 0)
  LOADB(By0,By1,By2,By3,By4,By5,By6,By7, 1)
  LOADA(A0_0, A0_1, A0_2, A0_3, 0)
  LOADA(A1_0, A1_1, A1_2, A1_3, 1)
  LOADA(A2_0, A2_1, A2_2, A2_3, 2)
  LOADA(A3_0, A3_1, A3_2, A3_3, 3)

  // Steady state, unrolled x4. Step t: MFMA(t) consumes A[t%4] (issued t-4)
  // and B[t%2] (issued t-2) — both among the OLDEST outstanding; the counted
  // vmcnt wait leaves A(t+2),A(t+3),B(t+1) in flight. Reloads AFTER consume.
  #pragma unroll 1
  for (int kk = 0; kk < KPAD / 4; ++kk) {
    const int ko = kk * 4;
    MFMA_STEP(A0_0, A0_1, A0_2, A0_3, Bx0,Bx1,Bx2,Bx3,Bx4,Bx5,Bx6,Bx7)
    if (ko + 2 < KPAD) LOADB(Bx0,Bx1,Bx2,Bx3,Bx4,Bx5,Bx6,Bx7, ko + 2)
    if (ko + 4 < KPAD) LOADA(A0_0, A0_1, A0_2, A0_3, ko + 4)

    MFMA_STEP(A1_0, A1_1, A1_2, A1_3, By0,By1,By2,By3,By4,By5,By6,By7)
    if (ko + 3 < KPAD) LOADB(By0,By1,By2,By3,By4,By5,By6,By7, ko + 3)
    if (ko + 5 < KPAD) LOADA(A1_0, A1_1, A1_2, A1_3, ko + 5)

    MFMA_STEP(A2_0, A2_1, A2_2, A2_3, Bx0,Bx1,Bx2,Bx3,Bx4,Bx5,Bx6,Bx7)
    if (ko + 4 < KPAD) LOADB(Bx0,Bx1,Bx2,Bx3,Bx4,Bx5,Bx6,Bx7, ko + 4)
    if (ko + 6 < KPAD) LOADA(A2_0, A2_1, A2_2, A2_3, ko + 6)

    MFMA_STEP(A3_0, A3_1, A3_2, A3_3, By0,By1,By2,By3,By4,By5,By6,By7)
    if (ko + 5 < KPAD) LOADB(By0,By1,By2,By3,By4,By5,By6,By7, ko + 5)
    if (ko + 7 < KPAD) LOADA(A3_0, A3_1, A3_2, A3_3, ko + 7)
  }
#undef LOADA
#undef LOADB
#undef MFMA_STEP

  // Epilogue: /denom + bias + residual. Non-temporal on the streaming fp32
  // traffic (residual read, out write) to preserve L2/L3 for the gather table.
  #pragma unroll
  for (int rt = 0; rt < 2; ++rt) {
    #pragma unroll
    for (int nt = 0; nt < 4; ++nt) {
      const int col = nt * 16 + lr;
      const float b = bias[col];
      #pragma unroll
      for (int i = 0; i < 4; ++i) {
        const int rl = wave * 32 + rt * 16 + lk * 4 + i;
        const int m  = m0 + rl;
        if (m < NPTS) {
          const float denom = (float)max(s_cnt[rl], 1);
          const float a = (rt == 0) ? acc0[nt][i] : acc1[nt][i];
          const float res = __builtin_nontemporal_load(&feats[(size_t)m * NCH + col]);
          __builtin_nontemporal_store(a / denom + b + res,
                                      &out[(size_t)m * NCH + col]);
        }
      }
    }
  }
}

extern "C" void kernel_launch(void* const* d_in, const int* in_sizes, int n_in,
                              void* d_out, int out_size, void* d_ws, size_t ws_size,
                              hipStream_t stream) {
  const float* feats    = (const float*)d_in[0];
  const int*   rulebook = (const int*)d_in[1];
  const float* weight   = (const float*)d_in[2];
  const float* bias     = (const float*)d_in[3];
  float* out = (float*)d_out;

  // Workspace: [0, ~6.4MB) feats fp8 (M+1 rows x 64B); then weights fp8 (112KB).
  unsigned char* f8 = (unsigned char*)d_ws;
  const size_t f8_bytes = (size_t)(NPTS + 1) * NCH;          // 6,400,064
  const size_t wt_off   = (f8_bytes + 511) & ~(size_t)511;
  unsigned char* wl = (unsigned char*)((char*)d_ws + wt_off);

  {
    const size_t total = (size_t)(NPTS + 1) * NCH;           // fp8 bytes
    const int threads = (int)((total + 15) / 16);
    convert_feats_kernel<<<(threads + 255) / 256, 256, 0, stream>>>(feats, f8);
  }
  {
    const int n = KPAD * NCH * NCH;
    convert_weight_kernel<<<(n + 255) / 256, 256, 0, stream>>>(weight, wl);
  }
  {
    const int nblk = (NPTS + 127) / 128;   // 782
    spconv_kernel<<<nblk, 256, 0, stream>>>(f8, rulebook, wl, feats, bias, out);
  }
}

// Round 11
// 94.986 us; speedup vs baseline: 1.0524x; 1.0524x over previous
//
#include <hip/hip_runtime.h>
#include <hip/hip_bf16.h>

// Problem constants: M=100000 points, K=27 offsets, Cin=Cout=64.
// R11: fp8 + cin-split 2-pass gather. feats-fp8 stored as TWO planes of 32
// channels, 3.2MB each (< 4MiB per-XCD L2). K-loop runs twice (plane 0 then
// plane 1), acc persists -> during each pass the gather working set is fully
// L2-resident per XCD. Schedule/layout otherwise identical to R9 (85us).
#define NPTS 100000
#define KOFF 27
#define KPAD 28          // padded K: tile 27 = zero weights + zero-row gathers
#define NCH  64
#define PLSTRIDE ((size_t)(NPTS + 1) * 32)   // bytes per cin-plane

typedef __attribute__((ext_vector_type(4))) float f32x4;
typedef __attribute__((ext_vector_type(4))) unsigned int u32x4;

// feats fp32 (M x 64) -> fp8 e4m3, cin-split planes: plane p holds channels
// [p*32, p*32+32) of every row, 32B/row. Row NPTS all-zero in both planes.
__global__ void convert_feats_kernel(const float* __restrict__ feats,
                                     unsigned char* __restrict__ f8) {
  size_t tid  = (size_t)blockIdx.x * blockDim.x + threadIdx.x;
  size_t base = tid * 16;                       // byte index in logical M x 64
  const size_t valid = (size_t)NPTS * NCH;
  const size_t total = valid + NCH;
  if (base >= total) return;
  unsigned int w0 = 0, w1 = 0, w2 = 0, w3 = 0;
  if (base < valid) {
    const float4 a = *reinterpret_cast<const float4*>(feats + base);
    const float4 b = *reinterpret_cast<const float4*>(feats + base + 4);
    const float4 c = *reinterpret_cast<const float4*>(feats + base + 8);
    const float4 d = *reinterpret_cast<const float4*>(feats + base + 12);
    int p;
    p = __builtin_amdgcn_cvt_pk_fp8_f32(a.x, a.y, 0, false);
    p = __builtin_amdgcn_cvt_pk_fp8_f32(a.z, a.w, p, true);  w0 = (unsigned)p;
    p = __builtin_amdgcn_cvt_pk_fp8_f32(b.x, b.y, 0, false);
    p = __builtin_amdgcn_cvt_pk_fp8_f32(b.z, b.w, p, true);  w1 = (unsigned)p;
    p = __builtin_amdgcn_cvt_pk_fp8_f32(c.x, c.y, 0, false);
    p = __builtin_amdgcn_cvt_pk_fp8_f32(c.z, c.w, p, true);  w2 = (unsigned)p;
    p = __builtin_amdgcn_cvt_pk_fp8_f32(d.x, d.y, 0, false);
    p = __builtin_amdgcn_cvt_pk_fp8_f32(d.z, d.w, p, true);  w3 = (unsigned)p;
  }
  const size_t m      = base >> 6;       // row
  const size_t within = base & 63;       // byte within row
  const size_t plane  = within >> 5;     // cin chunk
  unsigned char* dst = f8 + plane * PLSTRIDE + m * 32 + (within & 31);
  *reinterpret_cast<u32x4*>(dst) = u32x4{w0, w1, w2, w3};
}

// weight fp32 [k][cin][cout] -> fp8 e4m3 fragments grouped by cin-plane:
// frag id = (plane*KPAD + ko)*4 + nt (512B each); within frag lane L's 8B at
// L*8; kk = c&31 (k within plane): lane = ((kk>>3)<<4) | (o&15), byte = kk&7.
// Matches MFMA 16x16x32 B[k][n]: n = lane&15, k = 8*(lane>>4)+j. Pad ko zeros.
__global__ void convert_weight_kernel(const float* __restrict__ w,
                                      unsigned char* __restrict__ wt) {
  int tid = blockIdx.x * 256 + threadIdx.x;
  if (tid >= KPAD * NCH * NCH) return;
  int ko  = tid >> 12;
  int rem = tid & 4095;
  int c   = rem >> 6;
  int o   = rem & 63;
  float val = (ko < KOFF) ? w[(size_t)ko * 4096 + c * 64 + o] : 0.0f;
  int p8 = __builtin_amdgcn_cvt_pk_fp8_f32(val, 0.0f, 0, false);
  const int plane = c >> 5;
  const int kk    = c & 31;
  const int lane  = ((kk >> 3) << 4) | (o & 15);
  int dst = ((plane * KPAD + ko) * 4 + (o >> 4)) * 512 + lane * 8 + (kk & 7);
  wt[dst] = (unsigned char)(p8 & 0xff);
}

// Main kernel: block = 128 rows, 4 waves; wave owns 32 rows (2 row-tiles of
// 16) x 64 cout. Two passes over ko (one per cin-plane); acc carries across.
// Per ko per pass: 2 A-gathers (8B/lane, one 32B row-chunk each) + 4 B-frag
// loads (512B contiguous) + 8 MFMAs, R9 consume-immediate schedule.
__global__ __launch_bounds__(256, 4)
void spconv_kernel(const unsigned char* __restrict__ f8,       // 2 planes fp8
                   const int* __restrict__ rulebook,           // NPTS x 27 int32
                   const unsigned char* __restrict__ wl,       // plane-grouped fp8 W
                   const float* __restrict__ feats,            // NPTS x 64 fp32
                   const float* __restrict__ bias,             // 64 fp32
                   float* __restrict__ out) {                  // NPTS x 64 fp32
  __shared__ int s_off[128][KPAD];   // BYTE offsets within a plane (idx*32)
  __shared__ int s_cnt[128];

  const int tid = threadIdx.x;
  const int m0  = blockIdx.x * 128;

  if (tid < 128) s_cnt[tid] = 0;
  __syncthreads();

  for (int f = tid; f < 128 * KPAD; f += 256) {
    int r = f / KPAD, k = f - r * KPAD;
    int m = m0 + r;
    int off = NPTS * 32;
    if (m < NPTS && k < KOFF) {
      int v = rulebook[(size_t)m * KOFF + k];
      if (v >= 0) { off = v * 32; atomicAdd(&s_cnt[r], 1); }
    }
    s_off[r][k] = off;
  }
  __syncthreads();

  const int wave = tid >> 6;
  const int lane = tid & 63;
  const int lr   = lane & 15;
  const int lk   = lane >> 4;
  const int lk8  = lk * 8;             // byte offset within a 32B row-chunk
  const int row0 = wave * 32 + lr;
  const int row1 = wave * 32 + 16 + lr;

  f32x4 acc0[4] = {f32x4{0,0,0,0}, f32x4{0,0,0,0}, f32x4{0,0,0,0}, f32x4{0,0,0,0}};
  f32x4 acc1[4] = {f32x4{0,0,0,0}, f32x4{0,0,0,0}, f32x4{0,0,0,0}, f32x4{0,0,0,0}};

  // A: 2 sets (even/odd ko), one 8B reg per row-tile.
  long A0r0, A0r1, A1r0, A1r1;
  // B: single set (4 frags of this plane), reloaded after consumption.
  long B0, B1, B2, B3;

#define LOADA(R0, R1, FB, KO) {                                               \
    R0 = *reinterpret_cast<const long*>((FB) + (size_t)(unsigned)s_off[row0][(KO)] + lk8); \
    R1 = *reinterpret_cast<const long*>((FB) + (size_t)(unsigned)s_off[row1][(KO)] + lk8); \
  }

#define LOADB(WB, KO) {                                                       \
    const char* wb_ = (WB) + (size_t)(KO) * 2048;                             \
    B0 = *reinterpret_cast<const long*>(wb_ + 0 * 512);                       \
    B1 = *reinterpret_cast<const long*>(wb_ + 1 * 512);                       \
    B2 = *reinterpret_cast<const long*>(wb_ + 2 * 512);                       \
    B3 = *reinterpret_cast<const long*>(wb_ + 3 * 512);                       \
  }

#define MFMA8(R0, R1) {                                                       \
    acc0[0] = __builtin_amdgcn_mfma_f32_16x16x32_fp8_fp8(R0, B0, acc0[0],0,0,0);\
    acc1[0] = __builtin_amdgcn_mfma_f32_16x16x32_fp8_fp8(R1, B0, acc1[0],0,0,0);\
    acc0[1] = __builtin_amdgcn_mfma_f32_16x16x32_fp8_fp8(R0, B1, acc0[1],0,0,0);\
    acc1[1] = __builtin_amdgcn_mfma_f32_16x16x32_fp8_fp8(R1, B1, acc1[1],0,0,0);\
    acc0[2] = __builtin_amdgcn_mfma_f32_16x16x32_fp8_fp8(R0, B2, acc0[2],0,0,0);\
    acc1[2] = __builtin_amdgcn_mfma_f32_16x16x32_fp8_fp8(R1, B2, acc1[2],0,0,0);\
    acc0[3] = __builtin_amdgcn_mfma_f32_16x16x32_fp8_fp8(R0, B3, acc0[3],0,0,0);\
    acc1[3] = __builtin_amdgcn_mfma_f32_16x16x32_fp8_fp8(R1, B3, acc1[3],0,0,0);\
  }

  #pragma unroll 1
  for (int pass = 0; pass < 2; ++pass) {
    const char* fb_p = (const char*)f8 + (size_t)pass * PLSTRIDE;
    const char* wl_p = (const char*)wl + (size_t)pass * (KPAD * 2048) + lane * 8;

    LOADA(A0r0, A0r1, fb_p, 0)
    LOADA(A1r0, A1r1, fb_p, 1)
    LOADB(wl_p, 0)

    #pragma unroll 1
    for (int kk = 0; kk < KPAD / 2; ++kk) {
      const int ko = kk * 2;
      MFMA8(A0r0, A0r1)                                 // consumes A(ko), B(ko)
      LOADB(wl_p, ko + 1)
      if (ko + 2 < KPAD) LOADA(A0r0, A0r1, fb_p, ko + 2)
      MFMA8(A1r0, A1r1)                                 // consumes A(ko+1), B(ko+1)
      if (ko + 2 < KPAD) LOADB(wl_p, ko + 2)
      if (ko + 3 < KPAD) LOADA(A1r0, A1r1, fb_p, ko + 3)
    }
  }
#undef LOADA
#undef LOADB
#undef MFMA8

  // Epilogue: /denom + bias + residual (plain fp32 loads/stores, as R9).
  #pragma unroll
  for (int rt = 0; rt < 2; ++rt) {
    #pragma unroll
    for (int nt = 0; nt < 4; ++nt) {
      const int col = nt * 16 + lr;
      const float b = bias[col];
      #pragma unroll
      for (int i = 0; i < 4; ++i) {
        const int rl = wave * 32 + rt * 16 + lk * 4 + i;
        const int m  = m0 + rl;
        if (m < NPTS) {
          const float denom = (float)max(s_cnt[rl], 1);
          const float a = (rt == 0) ? acc0[nt][i] : acc1[nt][i];
          out[(size_t)m * NCH + col] =
              a / denom + b + feats[(size_t)m * NCH + col];
        }
      }
    }
  }
}

extern "C" void kernel_launch(void* const* d_in, const int* in_sizes, int n_in,
                              void* d_out, int out_size, void* d_ws, size_t ws_size,
                              hipStream_t stream) {
  const float* feats    = (const float*)d_in[0];
  const int*   rulebook = (const int*)d_in[1];
  const float* weight   = (const float*)d_in[2];
  const float* bias     = (const float*)d_in[3];
  float* out = (float*)d_out;

  // Workspace: [0, 2*PLSTRIDE) feats fp8 planes (~6.4MB); then weights fp8 (112KB).
  unsigned char* f8 = (unsigned char*)d_ws;
  const size_t f8_bytes = 2 * PLSTRIDE;                      // 6,400,064
  const size_t wt_off   = (f8_bytes + 511) & ~(size_t)511;
  unsigned char* wl = (unsigned char*)((char*)d_ws + wt_off);

  {
    const size_t total = (size_t)(NPTS + 1) * NCH;           // logical fp8 bytes
    const int threads = (int)((total + 15) / 16);
    convert_feats_kernel<<<(threads + 255) / 256, 256, 0, stream>>>(feats, f8);
  }
  {
    const int n = KPAD * NCH * NCH;
    convert_weight_kernel<<<(n + 255) / 256, 256, 0, stream>>>(weight, wl);
  }
  {
    const int nblk = (NPTS + 127) / 128;   // 782
    spconv_kernel<<<nblk, 256, 0, stream>>>(f8, rulebook, wl, feats, bias, out);
  }
}

// Round 12
// 70.069 us; speedup vs baseline: 1.4267x; 1.3556x over previous
//
#include <hip/hip_runtime.h>
#include <hip/hip_bf16.h>

// Problem constants: M=100000 points, K=27 offsets, Cin=Cout=64.
// R12: fp8, single-segment row gathers. feats-fp8 rows are byte-swizzled so
// ONE dwordx4 load (16B/lane, 4 lanes/row) reads the full 64B row as one
// cache segment; low/high 8B halves are the chunk0/chunk1 MFMA A-fragments.
// W pair-packed the same way (1KB blocks, 16B/lane). R9 schedule otherwise.
#define NPTS 100000
#define KOFF 27
#define KPAD 28          // padded K: tile 27 = zero weights + zero-row gathers
#define NCH  64

typedef __attribute__((ext_vector_type(4))) float f32x4;
typedef __attribute__((ext_vector_type(4))) unsigned int u32x4;
typedef __attribute__((ext_vector_type(2))) long long2_t;   // 16B, .x/.y = i64 halves

// feats fp32 (M x 64) -> fp8 e4m3 swizzled rows. Row byte p = lk*16 + h*8 + j
// holds channel c = h*32 + lk*8 + j (lk=0..3, h=0..1, j=0..7). Thread handles
// one (m, lk) 16B block. Row NPTS all-zero.
__global__ void convert_feats_kernel(const float* __restrict__ feats,
                                     unsigned char* __restrict__ f8) {
  int tid = blockIdx.x * 256 + threadIdx.x;
  const int total = (NPTS + 1) * 4;
  if (tid >= total) return;
  const int m  = tid >> 2;
  const int lk = tid & 3;
  unsigned int w0 = 0, w1 = 0, w2 = 0, w3 = 0;
  if (m < NPTS) {
    const float* r = feats + (size_t)m * NCH + lk * 8;
    const float4 a = *reinterpret_cast<const float4*>(r);          // c0 j0-3
    const float4 b = *reinterpret_cast<const float4*>(r + 4);      // c0 j4-7
    const float4 c = *reinterpret_cast<const float4*>(r + 32);     // c1 j0-3
    const float4 d = *reinterpret_cast<const float4*>(r + 36);     // c1 j4-7
    int p;
    p = __builtin_amdgcn_cvt_pk_fp8_f32(a.x, a.y, 0, false);
    p = __builtin_amdgcn_cvt_pk_fp8_f32(a.z, a.w, p, true);  w0 = (unsigned)p;
    p = __builtin_amdgcn_cvt_pk_fp8_f32(b.x, b.y, 0, false);
    p = __builtin_amdgcn_cvt_pk_fp8_f32(b.z, b.w, p, true);  w1 = (unsigned)p;
    p = __builtin_amdgcn_cvt_pk_fp8_f32(c.x, c.y, 0, false);
    p = __builtin_amdgcn_cvt_pk_fp8_f32(c.z, c.w, p, true);  w2 = (unsigned)p;
    p = __builtin_amdgcn_cvt_pk_fp8_f32(d.x, d.y, 0, false);
    p = __builtin_amdgcn_cvt_pk_fp8_f32(d.z, d.w, p, true);  w3 = (unsigned)p;
  }
  *reinterpret_cast<u32x4*>(f8 + (size_t)m * 64 + lk * 16) = u32x4{w0, w1, w2, w3};
}

// weight fp32 [k][cin][cout] -> fp8 pair-packed fragments: block (ko, nt) is
// 1KB; lane L's 16B at L*16; byte h*8+j holds W[ko][h*32 + 8*(L>>4) + j][
// nt*16 + (L&15)]. One 16B load/lane yields both chunk fragments (.x/.y).
__global__ void convert_weight_kernel(const float* __restrict__ w,
                                      unsigned char* __restrict__ wt) {
  int tid = blockIdx.x * 256 + threadIdx.x;
  if (tid >= KPAD * NCH * NCH) return;
  int ko  = tid >> 12;
  int rem = tid & 4095;
  int c   = rem >> 6;
  int o   = rem & 63;
  float val = (ko < KOFF) ? w[(size_t)ko * 4096 + c * 64 + o] : 0.0f;
  int p8 = __builtin_amdgcn_cvt_pk_fp8_f32(val, 0.0f, 0, false);
  const int h  = c >> 5;
  const int kk = c & 31;
  const int L  = ((kk >> 3) << 4) | (o & 15);
  int dst = ((ko * 4) + (o >> 4)) * 1024 + L * 16 + h * 8 + (kk & 7);
  wt[dst] = (unsigned char)(p8 & 0xff);
}

// Main kernel: block = 128 rows, 4 waves; wave owns 32 rows (2 row-tiles of
// 16) x 64 cout x 28 kos. Per ko: 2 A-loads (16B/lane, ONE segment per row)
// + 4 B-loads (16B/lane, 1KB contiguous) + 16 MFMAs. R9 consume-immediate
// schedule (measured best: 85us).
__global__ __launch_bounds__(256, 4)
void spconv_kernel(const unsigned char* __restrict__ f8,       // (NPTS+1) x 64 fp8 swz
                   const int* __restrict__ rulebook,           // NPTS x 27 int32
                   const unsigned char* __restrict__ wl,       // pair-packed fp8 W
                   const float* __restrict__ feats,            // NPTS x 64 fp32
                   const float* __restrict__ bias,             // 64 fp32
                   float* __restrict__ out) {                  // NPTS x 64 fp32
  __shared__ int s_off[128][KPAD];   // BYTE offsets into f8 (idx*64)
  __shared__ int s_cnt[128];

  const int tid = threadIdx.x;
  const int m0  = blockIdx.x * 128;

  if (tid < 128) s_cnt[tid] = 0;
  __syncthreads();

  for (int f = tid; f < 128 * KPAD; f += 256) {
    int r = f / KPAD, k = f - r * KPAD;
    int m = m0 + r;
    int off = NPTS * 64;
    if (m < NPTS && k < KOFF) {
      int v = rulebook[(size_t)m * KOFF + k];
      if (v >= 0) { off = v * 64; atomicAdd(&s_cnt[r], 1); }
    }
    s_off[r][k] = off;
  }
  __syncthreads();

  const int wave = tid >> 6;
  const int lane = tid & 63;
  const int lr   = lane & 15;
  const int lk   = lane >> 4;
  const int lk16 = lk * 16;            // byte offset of lane's 16B within row
  const int row0 = wave * 32 + lr;
  const int row1 = wave * 32 + 16 + lr;

  const char* fbase = (const char*)f8;
  const char* wlane = (const char*)wl + lane * 16;

  f32x4 acc0[4] = {f32x4{0,0,0,0}, f32x4{0,0,0,0}, f32x4{0,0,0,0}, f32x4{0,0,0,0}};
  f32x4 acc1[4] = {f32x4{0,0,0,0}, f32x4{0,0,0,0}, f32x4{0,0,0,0}, f32x4{0,0,0,0}};

  // A: 2 sets (even/odd ko) x 2 row-tiles, 16B each (.x=chunk0, .y=chunk1).
  long2_t A0r0, A0r1, A1r0, A1r1;
  // B: single set, 4 pair-packed frags (nt 0..3), reloaded after consumption.
  long2_t B0, B1, B2, B3;

#define LOADA(R0, R1, KO) {                                                   \
    R0 = *reinterpret_cast<const long2_t*>(fbase + (size_t)(unsigned)s_off[row0][(KO)] + lk16); \
    R1 = *reinterpret_cast<const long2_t*>(fbase + (size_t)(unsigned)s_off[row1][(KO)] + lk16); \
  }

#define LOADB(KO) {                                                           \
    const char* wb_ = wlane + (size_t)(KO) * 4096;                            \
    B0 = *reinterpret_cast<const long2_t*>(wb_ + 0 * 1024);                   \
    B1 = *reinterpret_cast<const long2_t*>(wb_ + 1 * 1024);                   \
    B2 = *reinterpret_cast<const long2_t*>(wb_ + 2 * 1024);                   \
    B3 = *reinterpret_cast<const long2_t*>(wb_ + 3 * 1024);                   \
  }

#define MFMA_STEP(R0, R1) {                                                   \
    acc0[0] = __builtin_amdgcn_mfma_f32_16x16x32_fp8_fp8(R0.x, B0.x, acc0[0],0,0,0);\
    acc0[0] = __builtin_amdgcn_mfma_f32_16x16x32_fp8_fp8(R0.y, B0.y, acc0[0],0,0,0);\
    acc1[0] = __builtin_amdgcn_mfma_f32_16x16x32_fp8_fp8(R1.x, B0.x, acc1[0],0,0,0);\
    acc1[0] = __builtin_amdgcn_mfma_f32_16x16x32_fp8_fp8(R1.y, B0.y, acc1[0],0,0,0);\
    acc0[1] = __builtin_amdgcn_mfma_f32_16x16x32_fp8_fp8(R0.x, B1.x, acc0[1],0,0,0);\
    acc0[1] = __builtin_amdgcn_mfma_f32_16x16x32_fp8_fp8(R0.y, B1.y, acc0[1],0,0,0);\
    acc1[1] = __builtin_amdgcn_mfma_f32_16x16x32_fp8_fp8(R1.x, B1.x, acc1[1],0,0,0);\
    acc1[1] = __builtin_amdgcn_mfma_f32_16x16x32_fp8_fp8(R1.y, B1.y, acc1[1],0,0,0);\
    acc0[2] = __builtin_amdgcn_mfma_f32_16x16x32_fp8_fp8(R0.x, B2.x, acc0[2],0,0,0);\
    acc0[2] = __builtin_amdgcn_mfma_f32_16x16x32_fp8_fp8(R0.y, B2.y, acc0[2],0,0,0);\
    acc1[2] = __builtin_amdgcn_mfma_f32_16x16x32_fp8_fp8(R1.x, B2.x, acc1[2],0,0,0);\
    acc1[2] = __builtin_amdgcn_mfma_f32_16x16x32_fp8_fp8(R1.y, B2.y, acc1[2],0,0,0);\
    acc0[3] = __builtin_amdgcn_mfma_f32_16x16x32_fp8_fp8(R0.x, B3.x, acc0[3],0,0,0);\
    acc0[3] = __builtin_amdgcn_mfma_f32_16x16x32_fp8_fp8(R0.y, B3.y, acc0[3],0,0,0);\
    acc1[3] = __builtin_amdgcn_mfma_f32_16x16x32_fp8_fp8(R1.x, B3.x, acc1[3],0,0,0);\
    acc1[3] = __builtin_amdgcn_mfma_f32_16x16x32_fp8_fp8(R1.y, B3.y, acc1[3],0,0,0);\
  }

  // Prologue: A(0), A(1), B(0) in flight.
  LOADA(A0r0, A0r1, 0)
  LOADA(A1r0, A1r1, 1)
  LOADB(0)

  #pragma unroll 1
  for (int kk = 0; kk < KPAD / 2; ++kk) {
    const int ko = kk * 2;
    MFMA_STEP(A0r0, A0r1)                         // consumes A(ko), B(ko)
    LOADB(ko + 1)
    if (ko + 2 < KPAD) LOADA(A0r0, A0r1, ko + 2)
    MFMA_STEP(A1r0, A1r1)                         // consumes A(ko+1), B(ko+1)
    if (ko + 2 < KPAD) LOADB(ko + 2)
    if (ko + 3 < KPAD) LOADA(A1r0, A1r1, ko + 3)
  }
#undef LOADA
#undef LOADB
#undef MFMA_STEP

  // Epilogue: /denom + bias + residual.
  #pragma unroll
  for (int rt = 0; rt < 2; ++rt) {
    #pragma unroll
    for (int nt = 0; nt < 4; ++nt) {
      const int col = nt * 16 + lr;
      const float b = bias[col];
      #pragma unroll
      for (int i = 0; i < 4; ++i) {
        const int rl = wave * 32 + rt * 16 + lk * 4 + i;
        const int m  = m0 + rl;
        if (m < NPTS) {
          const float denom = (float)max(s_cnt[rl], 1);
          const float a = (rt == 0) ? acc0[nt][i] : acc1[nt][i];
          out[(size_t)m * NCH + col] =
              a / denom + b + feats[(size_t)m * NCH + col];
        }
      }
    }
  }
}

extern "C" void kernel_launch(void* const* d_in, const int* in_sizes, int n_in,
                              void* d_out, int out_size, void* d_ws, size_t ws_size,
                              hipStream_t stream) {
  const float* feats    = (const float*)d_in[0];
  const int*   rulebook = (const int*)d_in[1];
  const float* weight   = (const float*)d_in[2];
  const float* bias     = (const float*)d_in[3];
  float* out = (float*)d_out;

  // Workspace: [0, ~6.4MB) feats fp8 swizzled rows; then weights fp8 (112KB).
  unsigned char* f8 = (unsigned char*)d_ws;
  const size_t f8_bytes = (size_t)(NPTS + 1) * NCH;          // 6,400,064
  const size_t wt_off   = (f8_bytes + 1023) & ~(size_t)1023;
  unsigned char* wl = (unsigned char*)((char*)d_ws + wt_off);

  {
    const int total = (NPTS + 1) * 4;                        // 16B blocks
    convert_feats_kernel<<<(total + 255) / 256, 256, 0, stream>>>(feats, f8);
  }
  {
    const int n = KPAD * NCH * NCH;
    convert_weight_kernel<<<(n + 255) / 256, 256, 0, stream>>>(weight, wl);
  }
  {
    const int nblk = (NPTS + 127) / 128;   // 782
    spconv_kernel<<<nblk, 256, 0, stream>>>(f8, rulebook, wl, feats, bias, out);
  }
}